// Round 22
// baseline (470.485 us; speedup 1.0000x reference)
//
#include <hip/hip_runtime.h>
#include <hip/hip_bf16.h>

#define H 128
#define LN_EPS 1e-5f
#define EW_BLOCKS 4096

typedef __attribute__((ext_vector_type(8))) short bf16x8;
typedef __attribute__((ext_vector_type(4))) float f32x4;

static __device__ __forceinline__ unsigned short f2bf(float f) {
  unsigned u = __float_as_uint(f);
  unsigned r = (u + 0x7fff + ((u >> 16) & 1)) >> 16;
  return (unsigned short)r;
}
static __device__ __forceinline__ float bf2f(unsigned short s) {
  return __uint_as_float(((unsigned)s) << 16);
}

// ---------------- K1: union {edge_weight | count | prep_cvec | pack_w} ----------------
__global__ __launch_bounds__(256) void pre1_kernel(
    const int* __restrict__ ei, const float* __restrict__ af, const float* __restrict__ We1,
    const float* __restrict__ be1, const float* __restrict__ We2, const float* __restrict__ be2,
    float* __restrict__ ew, int* __restrict__ cnt, const float* __restrict__ Wf,
    const float* __restrict__ bf, float* __restrict__ cvec, const float* __restrict__ Wrel,
    const float* __restrict__ Wroot, const float* __restrict__ Wd1,
    unsigned short* __restrict__ wpk, int E, int cntBlocks) {
  int b = blockIdx.x;
  int tid = threadIdx.x;
  if (b < EW_BLOCKS) {
    // one lane per edge; We1/be1/We2 wave-uniform -> scalar loads
    int gid = b * 256 + tid;
    int stride = EW_BLOCKS * 256;
    float b2 = be2[0];
    for (int e = gid; e < E; e += stride) {
      float4 a0 = *(const float4*)&af[(size_t)e * 8];
      float4 a1 = *(const float4*)&af[(size_t)e * 8 + 4];
      float acc = 0.f;
#pragma unroll 4
      for (int c = 0; c < H; ++c) {
        float t = be1[c];
        t += a0.x * We1[0 * H + c];
        t += a0.y * We1[1 * H + c];
        t += a0.z * We1[2 * H + c];
        t += a0.w * We1[3 * H + c];
        t += a1.x * We1[4 * H + c];
        t += a1.y * We1[5 * H + c];
        t += a1.z * We1[6 * H + c];
        t += a1.w * We1[7 * H + c];
        acc += fmaxf(t, 0.f) * We2[c];
      }
      float s = acc + b2;
      ew[e] = 1.f / (1.f + expf(-s));
    }
  } else if (b < EW_BLOCKS + cntBlocks) {
    int e = (b - EW_BLOCKS) * 256 + tid;
    if (e < E) atomicAdd(&cnt[ei[E + e]], 1);
  } else if (b == EW_BLOCKS + cntBlocks) {
    __shared__ float part[2][128];
    int col = tid & 127, seg = tid >> 7;
    float s = 0.f;
    for (int r = seg * 64; r < seg * 64 + 64; ++r) s += Wf[r * H + col];
    part[seg][col] = s;
    __syncthreads();
    if (tid < 128) cvec[tid] = bf[tid] + part[0][tid] + part[1][tid];
  } else {
    int id = (b - (EW_BLOCKS + cntBlocks + 1)) * 256 + tid;
    if (id >= 9 * 2048) return;
    int l = id & 63, nf = (id >> 6) & 7, kk = (id >> 9) & 3, m = id >> 11;
    const float* src;
    if (m == 0) src = Wf + H * H;
    else if (m <= 3) src = Wrel + (size_t)(m - 1) * H * H;
    else if (m <= 6) src = Wroot + (size_t)(m - 4) * H * H;
    else src = Wd1 + (size_t)(m - 7) * H * H;
    int col = nf * 16 + (l & 15);
    int kbase = kk * 32 + (l >> 4) * 8;
    unsigned short t[8];
#pragma unroll
    for (int j = 0; j < 8; ++j) t[j] = f2bf(src[(size_t)(kbase + j) * H + col]);
    *(uint4*)&wpk[(size_t)id * 8] = *(uint4*)t;
  }
}

// ---------------- K2: union {gemm_init | scan} ----------------
__global__ __launch_bounds__(256) void pre2_kernel(
    const float* __restrict__ Xf, const unsigned short* __restrict__ Wp,
    const float* __restrict__ cvec, unsigned short* __restrict__ Y,
    const int* __restrict__ cnt, int* __restrict__ off, int* __restrict__ pos, int M,
    int gblocks) {
  int b = blockIdx.x;
  int tid = threadIdx.x;
  if (b < gblocks) {
    int l = tid & 63, w = tid >> 6;
    int lr = l & 15, lg = l >> 4;
    int m0 = b * 128 + w * 32;
    f32x4 acc[2][8] = {};
    for (int kk = 0; kk < 4; ++kk) {
      bf16x8 a[2];
#pragma unroll
      for (int mi = 0; mi < 2; ++mi) {
        int row = m0 + mi * 16 + lr;
        if (row >= M) row = M - 1;
        const float* xp = &Xf[(size_t)row * H + kk * 32 + lg * 8];
        float4 u0 = *(const float4*)xp;
        float4 u1 = *(const float4*)(xp + 4);
        unsigned short t[8] = {f2bf(u0.x), f2bf(u0.y), f2bf(u0.z), f2bf(u0.w),
                               f2bf(u1.x), f2bf(u1.y), f2bf(u1.z), f2bf(u1.w)};
        a[mi] = *(const bf16x8*)t;
      }
#pragma unroll
      for (int nf = 0; nf < 8; ++nf) {
        bf16x8 bb = *(const bf16x8*)&Wp[(size_t)(kk * 8 + nf) * 512 + l * 8];
#pragma unroll
        for (int mi = 0; mi < 2; ++mi)
          acc[mi][nf] = __builtin_amdgcn_mfma_f32_16x16x32_bf16(a[mi], bb, acc[mi][nf], 0, 0, 0);
      }
    }
    float bv[8];
#pragma unroll
    for (int nf = 0; nf < 8; ++nf) bv[nf] = cvec[nf * 16 + lr];
#pragma unroll
    for (int mi = 0; mi < 2; ++mi)
#pragma unroll
      for (int r = 0; r < 4; ++r) {
        int row = m0 + mi * 16 + lg * 4 + r;
        if (row < M) {
#pragma unroll
          for (int nf = 0; nf < 8; ++nf)
            Y[(size_t)row * H + nf * 16 + lr] = f2bf(fmaxf(acc[mi][nf][r] + bv[nf], 0.f));
        }
      }
  } else {
    __shared__ int wtot[4];
    __shared__ int wbase[4];
    __shared__ int s_btot;
    __shared__ int s_carry;
    int N = M;
    int lane = tid & 63, wid = tid >> 6;
    if (tid == 0) s_carry = 0;
    __syncthreads();
    for (int base = 0; base < N; base += 1024) {
      int i0 = base + tid * 4;
      int v[4];
#pragma unroll
      for (int j = 0; j < 4; ++j) v[j] = (i0 + j < N) ? cnt[i0 + j] : 0;
      int s = v[0] + v[1] + v[2] + v[3];
      int incl = s;
#pragma unroll
      for (int o = 1; o < 64; o <<= 1) {
        int t = __shfl_up(incl, o, 64);
        if (lane >= o) incl += t;
      }
      if (lane == 63) wtot[wid] = incl;
      __syncthreads();
      if (tid == 0) {
        int run = 0;
        for (int w = 0; w < 4; ++w) { wbase[w] = run; run += wtot[w]; }
        s_btot = run;
      }
      __syncthreads();
      int e0 = s_carry + wbase[wid] + (incl - s);
#pragma unroll
      for (int j = 0; j < 4; ++j) {
        if (i0 + j < N) { off[i0 + j] = e0; pos[i0 + j] = e0; }
        e0 += v[j];
      }
      __syncthreads();
      if (tid == 0) s_carry += s_btot;
      __syncthreads();
    }
    if (tid == 0) off[N] = s_carry;
  }
}

// ---------------- fill: per-thread, one packed 16B CSR entry per edge ----------------
__global__ void fill_v2_kernel(const int* __restrict__ ei, const float* __restrict__ ew, int E,
                               int* __restrict__ pos, uint4* __restrict__ csr4) {
  int e = blockIdx.x * blockDim.x + threadIdx.x;
  if (e < E) {
    int d = ei[E + e];
    int p = atomicAdd(&pos[d], 1);
    csr4[p] = make_uint4((unsigned)ei[e], __float_as_uint(ew[e]), (unsigned)e, (unsigned)d);
  }
}

// ---------------- layer GEMM + LN + relu + residual (in-place x), MI=2 ----------------
__global__ __launch_bounds__(256) void gemm_layer_ln_kernel(
    const unsigned short* __restrict__ Agg, const unsigned short* __restrict__ WpRel,
    unsigned short* __restrict__ Xio, const unsigned short* __restrict__ WpRoot,
    const float* __restrict__ brel, const float* __restrict__ gamma,
    const float* __restrict__ beta, int M) {
  int l = threadIdx.x & 63, w = threadIdx.x >> 6;
  int lr = l & 15, lg = l >> 4;
  int m0 = blockIdx.x * 128 + w * 32;
  f32x4 acc[2][8] = {};
  for (int kk = 0; kk < 8; ++kk) {
    const unsigned short* X = (kk >= 4) ? Xio : Agg;
    const unsigned short* Wp = (kk >= 4) ? WpRoot : WpRel;
    int k4 = kk & 3;
    bf16x8 a[2] = {};
#pragma unroll
    for (int mi = 0; mi < 2; ++mi) {
      int row = m0 + mi * 16 + lr;
      if (row < M) a[mi] = *(const bf16x8*)&X[(size_t)row * H + k4 * 32 + lg * 8];
    }
#pragma unroll
    for (int nf = 0; nf < 8; ++nf) {
      bf16x8 b = *(const bf16x8*)&Wp[(size_t)(k4 * 8 + nf) * 512 + l * 8];
#pragma unroll
      for (int mi = 0; mi < 2; ++mi)
        acc[mi][nf] = __builtin_amdgcn_mfma_f32_16x16x32_bf16(a[mi], b, acc[mi][nf], 0, 0, 0);
    }
  }
  float bv[8], gv[8], bev[8];
#pragma unroll
  for (int nf = 0; nf < 8; ++nf) {
    int col = nf * 16 + lr;
    bv[nf] = brel[col]; gv[nf] = gamma[col]; bev[nf] = beta[col];
  }
#pragma unroll
  for (int mi = 0; mi < 2; ++mi) {
#pragma unroll
    for (int r = 0; r < 4; ++r) {
      int row = m0 + mi * 16 + lg * 4 + r;
      float hv[8], s1 = 0.f;
#pragma unroll
      for (int nf = 0; nf < 8; ++nf) { hv[nf] = acc[mi][nf][r] + bv[nf]; s1 += hv[nf]; }
      s1 += __shfl_xor(s1, 1, 64);
      s1 += __shfl_xor(s1, 2, 64);
      s1 += __shfl_xor(s1, 4, 64);
      s1 += __shfl_xor(s1, 8, 64);
      float mu = s1 * (1.0f / H);
      float s2 = 0.f;
#pragma unroll
      for (int nf = 0; nf < 8; ++nf) { float d = hv[nf] - mu; s2 += d * d; }
      s2 += __shfl_xor(s2, 1, 64);
      s2 += __shfl_xor(s2, 2, 64);
      s2 += __shfl_xor(s2, 4, 64);
      s2 += __shfl_xor(s2, 8, 64);
      float rstd = rsqrtf(s2 * (1.0f / H) + LN_EPS);
      if (row < M) {
#pragma unroll
        for (int nf = 0; nf < 8; ++nf) {
          int col = nf * 16 + lr;
          float v = fmaxf((hv[nf] - mu) * rstd * gv[nf] + bev[nf], 0.f);
          v += bf2f(Xio[(size_t)row * H + col]);
          Xio[(size_t)row * H + col] = f2bf(v);
        }
      }
    }
  }
}

// ---------------- decoder GEMMs fused: A = x@Wd1a + bd1 ; B = x@Wd1b, MI=2 ----------------
__global__ __launch_bounds__(256) void gemm_dec_kernel(
    const unsigned short* __restrict__ X, const unsigned short* __restrict__ WpA,
    const unsigned short* __restrict__ WpB, const float* __restrict__ bd1,
    unsigned short* __restrict__ Aout, unsigned short* __restrict__ Bout, int M) {
  int l = threadIdx.x & 63, w = threadIdx.x >> 6;
  int lr = l & 15, lg = l >> 4;
  int m0 = blockIdx.x * 128 + w * 32;
  f32x4 accA[2][8] = {};
  f32x4 accB[2][8] = {};
  for (int kk = 0; kk < 4; ++kk) {
    bf16x8 a[2];
#pragma unroll
    for (int mi = 0; mi < 2; ++mi) {
      int row = m0 + mi * 16 + lr;
      if (row >= M) row = M - 1;
      a[mi] = *(const bf16x8*)&X[(size_t)row * H + kk * 32 + lg * 8];
    }
#pragma unroll
    for (int nf = 0; nf < 8; ++nf) {
      bf16x8 bA = *(const bf16x8*)&WpA[(size_t)(kk * 8 + nf) * 512 + l * 8];
      bf16x8 bB = *(const bf16x8*)&WpB[(size_t)(kk * 8 + nf) * 512 + l * 8];
#pragma unroll
      for (int mi = 0; mi < 2; ++mi) {
        accA[mi][nf] = __builtin_amdgcn_mfma_f32_16x16x32_bf16(a[mi], bA, accA[mi][nf], 0, 0, 0);
        accB[mi][nf] = __builtin_amdgcn_mfma_f32_16x16x32_bf16(a[mi], bB, accB[mi][nf], 0, 0, 0);
      }
    }
  }
  float bdv[8];
#pragma unroll
  for (int nf = 0; nf < 8; ++nf) bdv[nf] = bd1[nf * 16 + lr];
#pragma unroll
  for (int mi = 0; mi < 2; ++mi)
#pragma unroll
    for (int r = 0; r < 4; ++r) {
      int row = m0 + mi * 16 + lg * 4 + r;
      if (row < M) {
#pragma unroll
        for (int nf = 0; nf < 8; ++nf) {
          int col = nf * 16 + lr;
          Aout[(size_t)row * H + col] = f2bf(accA[mi][nf][r] + bdv[nf]);
          Bout[(size_t)row * H + col] = f2bf(accB[mi][nf][r]);
        }
      }
    }
}

// ---------------- gather v4: 4 nodes/wave (16 lanes each, uint4 loads), 16-deep chunks ----------------
__global__ __launch_bounds__(256) void gather_agg_v4_kernel(
    const unsigned short* __restrict__ xbf, const int* __restrict__ off,
    const uint4* __restrict__ csr4, unsigned short* __restrict__ aggbf, int N) {
  int gw = (blockIdx.x * blockDim.x + threadIdx.x) >> 6;
  int lane = threadIdx.x & 63;
  int q = lane >> 4, li = lane & 15;
  int n = gw * 4 + q;
  if (n >= N) return;
  int s0 = off[n], s1 = off[n + 1];
  float a0 = 0.f, a1 = 0.f, a2 = 0.f, a3 = 0.f, a4 = 0.f, a5 = 0.f, a6 = 0.f, a7 = 0.f;
  for (int base = s0; base < s1; base += 16) {
    uint2 c[16];
#pragma unroll
    for (int j = 0; j < 16; ++j) {
      int id = base + j;
      c[j] = *(const uint2*)&csr4[id < s1 ? id : s1 - 1];
      if (id >= s1) c[j].y = 0;
    }
    uint4 v[16];
#pragma unroll
    for (int j = 0; j < 16; ++j)
      v[j] = *(const uint4*)&xbf[(size_t)c[j].x * H + li * 8];
#pragma unroll
    for (int j = 0; j < 16; ++j) {
      float w = __uint_as_float(c[j].y);
      a0 += w * bf2f((unsigned short)(v[j].x & 0xffffu));
      a1 += w * bf2f((unsigned short)(v[j].x >> 16));
      a2 += w * bf2f((unsigned short)(v[j].y & 0xffffu));
      a3 += w * bf2f((unsigned short)(v[j].y >> 16));
      a4 += w * bf2f((unsigned short)(v[j].z & 0xffffu));
      a5 += w * bf2f((unsigned short)(v[j].z >> 16));
      a6 += w * bf2f((unsigned short)(v[j].w & 0xffffu));
      a7 += w * bf2f((unsigned short)(v[j].w >> 16));
    }
  }
  unsigned short t[8] = {f2bf(a0), f2bf(a1), f2bf(a2), f2bf(a3),
                         f2bf(a4), f2bf(a5), f2bf(a6), f2bf(a7)};
  *(uint4*)&aggbf[(size_t)n * H + li * 8] = *(uint4*)t;
}

// ---------------- edge decoder v8: ONE LANE PER EDGE, column loop, wave-uniform weights ----------------
// Wd1c/Wd2 indices are lane-invariant -> scalar (SGPR) loads; no per-lane weight arrays, no shuffles.
__global__ __launch_bounds__(256) void edge_out_v8_kernel(
    const uint4* __restrict__ csr4, const float* __restrict__ af,
    const unsigned short* __restrict__ A, const unsigned short* __restrict__ B,
    const float* __restrict__ Wd1c, const float* __restrict__ Wd2,
    const float* __restrict__ bd2, float* __restrict__ out, int Ecnt) {
  int idx = blockIdx.x * blockDim.x + threadIdx.x;
  if (idx >= Ecnt) return;
  uint4 c = csr4[idx];
  const unsigned short* Arow = &A[(size_t)c.x * H];
  const unsigned short* Brow = &B[(size_t)c.w * H];
  float4 f0 = *(const float4*)&af[(size_t)c.z * 8];
  float4 f1 = *(const float4*)&af[(size_t)c.z * 8 + 4];
  float afv[8] = {f0.x, f0.y, f0.z, f0.w, f1.x, f1.y, f1.z, f1.w};
  float acc = 0.f;
#pragma unroll 4
  for (int ch = 0; ch < 16; ++ch) {  // 16 chunks x 8 cols
    uint4 va = *(const uint4*)&Arow[ch * 8];
    uint4 vb = *(const uint4*)&Brow[ch * 8];
    const unsigned* pa = (const unsigned*)&va;
    const unsigned* pb = (const unsigned*)&vb;
#pragma unroll
    for (int q = 0; q < 4; ++q) {
      int c0 = ch * 8 + q * 2;
      float t0 = bf2f((unsigned short)(pa[q] & 0xffffu)) + bf2f((unsigned short)(pb[q] & 0xffffu));
      float t1 = bf2f((unsigned short)(pa[q] >> 16)) + bf2f((unsigned short)(pb[q] >> 16));
#pragma unroll
      for (int i = 0; i < 8; ++i) {
        t0 += afv[i] * Wd1c[i * H + c0];
        t1 += afv[i] * Wd1c[i * H + c0 + 1];
      }
      acc += fmaxf(t0, 0.f) * Wd2[c0];
      acc += fmaxf(t1, 0.f) * Wd2[c0 + 1];
    }
  }
  out[c.z] = acc + bd2[0];
}

// ---------------- edge decoder v6: edge-parallel in CSR order (dst-locality for B) ----------------
__global__ __launch_bounds__(256) void edge_out_v6_kernel(
    const uint4* __restrict__ csr4, const float* __restrict__ af,
    const unsigned short* __restrict__ A, const unsigned short* __restrict__ B,
    const float* __restrict__ Wd1c, const float* __restrict__ Wd2,
    const float* __restrict__ bd2, float* __restrict__ out, int E) {
  int lane = threadIdx.x & 63;
  int sub = lane & 15;
  int grp = lane >> 4;
  float wc[8][8], w2[8];
#pragma unroll
  for (int i = 0; i < 8; ++i)
#pragma unroll
    for (int c = 0; c < 8; ++c) wc[i][c] = Wd1c[i * H + sub * 8 + c];
#pragma unroll
  for (int c = 0; c < 8; ++c) w2[c] = Wd2[sub * 8 + c];
  float b2 = bd2[0];
  int gw = (blockIdx.x * blockDim.x + threadIdx.x) >> 6;
  int nw = (gridDim.x * blockDim.x) >> 6;
  int n4 = (E + 3) >> 2;
  for (int e4 = gw; e4 < n4; e4 += nw) {
    int idx = e4 * 4 + grp;
    bool valid = idx < E;
    int ii = valid ? idx : E - 1;
    uint4 c = csr4[ii];
    uint4 va = *(const uint4*)&A[(size_t)c.x * H + sub * 8];
    uint4 vb = *(const uint4*)&B[(size_t)c.w * H + sub * 8];
    float4 f0 = *(const float4*)&af[(size_t)c.z * 8];
    float4 f1 = *(const float4*)&af[(size_t)c.z * 8 + 4];
    const unsigned* pa = (const unsigned*)&va;
    const unsigned* pb = (const unsigned*)&vb;
    float t[8];
#pragma unroll
    for (int q = 0; q < 4; ++q) {
      t[q * 2 + 0] = bf2f((unsigned short)(pa[q] & 0xffffu)) + bf2f((unsigned short)(pb[q] & 0xffffu));
      t[q * 2 + 1] = bf2f((unsigned short)(pa[q] >> 16)) + bf2f((unsigned short)(pb[q] >> 16));
    }
    float afv[8] = {f0.x, f0.y, f0.z, f0.w, f1.x, f1.y, f1.z, f1.w};
#pragma unroll
    for (int i = 0; i < 8; ++i)
#pragma unroll
      for (int cc = 0; cc < 8; ++cc) t[cc] += afv[i] * wc[i][cc];
    float p = 0.f;
#pragma unroll
    for (int cc = 0; cc < 8; ++cc) p += fmaxf(t[cc], 0.f) * w2[cc];
    p += __shfl_xor(p, 1, 64);
    p += __shfl_xor(p, 2, 64);
    p += __shfl_xor(p, 4, 64);
    p += __shfl_xor(p, 8, 64);
    if (valid && sub == 0) out[c.z] = p + b2;
  }
}

// ---------------- launch ----------------
extern "C" void kernel_launch(void* const* d_in, const int* in_sizes, int n_in, void* d_out,
                              int out_size, void* d_ws, size_t ws_size, hipStream_t stream) {
  const int* ei = (const int*)d_in[0];
  const float* af = (const float*)d_in[1];
  const float* h_old = (const float*)d_in[2];
  const float* Wf = (const float*)d_in[4];
  const float* bf = (const float*)d_in[5];
  const float* We1 = (const float*)d_in[6];
  const float* be1 = (const float*)d_in[7];
  const float* We2 = (const float*)d_in[8];
  const float* be2 = (const float*)d_in[9];
  const float* Wrel = (const float*)d_in[10];
  const float* brel = (const float*)d_in[11];
  const float* Wroot = (const float*)d_in[12];
  const float* gamma = (const float*)d_in[13];
  const float* beta = (const float*)d_in[14];
  const float* Wd1 = (const float*)d_in[15];
  const float* bd1 = (const float*)d_in[16];
  const float* Wd2 = (const float*)d_in[17];
  const float* bd2 = (const float*)d_in[18];
  const int N = in_sizes[2] / H;
  const int E = in_sizes[1] / 8;
  float* out = (float*)d_out;

  char* p = (char*)d_ws;
  auto alloc = [&](size_t b) { char* r = p; p += (b + 255) & ~(size_t)255; return r; };
  int* cnt = (int*)alloc((size_t)N * 4);
  int* pos = (int*)alloc((size_t)N * 4);
  int* off = (int*)alloc((size_t)(N + 1) * 4);
  uint4* csr4 = (uint4*)alloc((size_t)E * 16);
  float* ew = (float*)alloc((size_t)E * 4);
  float* cvec = (float*)alloc(H * 4);
  unsigned short* wpk = (unsigned short*)alloc((size_t)9 * 16384 * 2);
  unsigned short* xbf = (unsigned short*)alloc((size_t)N * H * 2);
  unsigned short* aggbf = (unsigned short*)alloc((size_t)N * H * 2);
  unsigned short* buf2 = (unsigned short*)alloc((size_t)N * H * 2);

  unsigned short* Abf = aggbf;  // reuse after layer loop
  unsigned short* Bbf = buf2;

  int cntBlocks = (E + 255) / 256;
  int gblocks = (N + 127) / 128;

  hipMemsetAsync(cnt, 0, (size_t)N * 4, stream);
  hipLaunchKernelGGL(pre1_kernel, dim3(EW_BLOCKS + cntBlocks + 1 + 72), dim3(256), 0, stream,
                     ei, af, We1, be1, We2, be2, ew, cnt, Wf, bf, cvec, Wrel, Wroot, Wd1, wpk,
                     E, cntBlocks);
  hipLaunchKernelGGL(pre2_kernel, dim3(gblocks + 1), dim3(256), 0, stream, h_old, wpk, cvec,
                     xbf, cnt, off, pos, N, gblocks);
  hipLaunchKernelGGL(fill_v2_kernel, dim3(cntBlocks), dim3(256), 0, stream, ei, ew, E, pos,
                     csr4);

  int gat4_blocks = (N + 15) / 16;
  for (int l = 0; l < 3; ++l) {
    hipLaunchKernelGGL(gather_agg_v4_kernel, dim3(gat4_blocks), dim3(256), 0, stream, xbf, off,
                       csr4, aggbf, N);
    hipLaunchKernelGGL(gemm_layer_ln_kernel, dim3(gblocks), dim3(256), 0, stream, aggbf,
                       wpk + (size_t)(1 + l) * 16384, xbf, wpk + (size_t)(4 + l) * 16384,
                       brel + l * H, gamma + l * H, beta + l * H, N);
  }

  hipLaunchKernelGGL(gemm_dec_kernel, dim3(gblocks), dim3(256), 0, stream, xbf,
                     wpk + (size_t)7 * 16384, wpk + (size_t)8 * 16384, bd1, Abf, Bbf, N);
  // in-run A/B: first half of CSR edges -> v8 (lane-per-edge, uniform weights),
  // second half -> v6 (16-lane groups). Disjoint out[eid] writes.
  int Ehalf = E / 2;
  hipLaunchKernelGGL(edge_out_v8_kernel, dim3((Ehalf + 255) / 256), dim3(256), 0, stream, csr4,
                     af, Abf, Bbf, Wd1 + 2 * H * H, Wd2, bd2, out, Ehalf);
  hipLaunchKernelGGL(edge_out_v6_kernel, dim3(2048), dim3(256), 0, stream, csr4 + Ehalf, af,
                     Abf, Bbf, Wd1 + 2 * H * H, Wd2, bd2, out, E - Ehalf);
}

// Round 23
// 423.615 us; speedup vs baseline: 1.1106x; 1.1106x over previous
//
#include <hip/hip_runtime.h>
#include <hip/hip_bf16.h>

#define H 128
#define LN_EPS 1e-5f
#define EW_BLOCKS 4096

typedef __attribute__((ext_vector_type(8))) short bf16x8;
typedef __attribute__((ext_vector_type(4))) float f32x4;

static __device__ __forceinline__ unsigned short f2bf(float f) {
  unsigned u = __float_as_uint(f);
  unsigned r = (u + 0x7fff + ((u >> 16) & 1)) >> 16;
  return (unsigned short)r;
}
static __device__ __forceinline__ float bf2f(unsigned short s) {
  return __uint_as_float(((unsigned)s) << 16);
}

// ---------------- K1: union {edge_weight | count | prep_cvec | pack_w} ----------------
__global__ __launch_bounds__(256) void pre1_kernel(
    const int* __restrict__ ei, const float* __restrict__ af, const float* __restrict__ We1,
    const float* __restrict__ be1, const float* __restrict__ We2, const float* __restrict__ be2,
    float* __restrict__ ew, int* __restrict__ cnt, const float* __restrict__ Wf,
    const float* __restrict__ bf, float* __restrict__ cvec, const float* __restrict__ Wrel,
    const float* __restrict__ Wroot, const float* __restrict__ Wd1,
    unsigned short* __restrict__ wpk, int E, int cntBlocks) {
  int b = blockIdx.x;
  int tid = threadIdx.x;
  if (b < EW_BLOCKS) {
    // one lane per edge; We1/be1/We2 wave-uniform -> scalar loads
    int gid = b * 256 + tid;
    int stride = EW_BLOCKS * 256;
    float b2 = be2[0];
    for (int e = gid; e < E; e += stride) {
      float4 a0 = *(const float4*)&af[(size_t)e * 8];
      float4 a1 = *(const float4*)&af[(size_t)e * 8 + 4];
      float acc = 0.f;
#pragma unroll 4
      for (int c = 0; c < H; ++c) {
        float t = be1[c];
        t += a0.x * We1[0 * H + c];
        t += a0.y * We1[1 * H + c];
        t += a0.z * We1[2 * H + c];
        t += a0.w * We1[3 * H + c];
        t += a1.x * We1[4 * H + c];
        t += a1.y * We1[5 * H + c];
        t += a1.z * We1[6 * H + c];
        t += a1.w * We1[7 * H + c];
        acc += fmaxf(t, 0.f) * We2[c];
      }
      float s = acc + b2;
      ew[e] = 1.f / (1.f + expf(-s));
    }
  } else if (b < EW_BLOCKS + cntBlocks) {
    int e = (b - EW_BLOCKS) * 256 + tid;
    if (e < E) atomicAdd(&cnt[ei[E + e]], 1);
  } else if (b == EW_BLOCKS + cntBlocks) {
    __shared__ float part[2][128];
    int col = tid & 127, seg = tid >> 7;
    float s = 0.f;
    for (int r = seg * 64; r < seg * 64 + 64; ++r) s += Wf[r * H + col];
    part[seg][col] = s;
    __syncthreads();
    if (tid < 128) cvec[tid] = bf[tid] + part[0][tid] + part[1][tid];
  } else {
    int id = (b - (EW_BLOCKS + cntBlocks + 1)) * 256 + tid;
    if (id >= 9 * 2048) return;
    int l = id & 63, nf = (id >> 6) & 7, kk = (id >> 9) & 3, m = id >> 11;
    const float* src;
    if (m == 0) src = Wf + H * H;
    else if (m <= 3) src = Wrel + (size_t)(m - 1) * H * H;
    else if (m <= 6) src = Wroot + (size_t)(m - 4) * H * H;
    else src = Wd1 + (size_t)(m - 7) * H * H;
    int col = nf * 16 + (l & 15);
    int kbase = kk * 32 + (l >> 4) * 8;
    unsigned short t[8];
#pragma unroll
    for (int j = 0; j < 8; ++j) t[j] = f2bf(src[(size_t)(kbase + j) * H + col]);
    *(uint4*)&wpk[(size_t)id * 8] = *(uint4*)t;
  }
}

// ---------------- K2: union {gemm_init | scan} ----------------
__global__ __launch_bounds__(256) void pre2_kernel(
    const float* __restrict__ Xf, const unsigned short* __restrict__ Wp,
    const float* __restrict__ cvec, unsigned short* __restrict__ Y,
    const int* __restrict__ cnt, int* __restrict__ off, int* __restrict__ pos, int M,
    int gblocks) {
  int b = blockIdx.x;
  int tid = threadIdx.x;
  if (b < gblocks) {
    int l = tid & 63, w = tid >> 6;
    int lr = l & 15, lg = l >> 4;
    int m0 = b * 128 + w * 32;
    f32x4 acc[2][8] = {};
    for (int kk = 0; kk < 4; ++kk) {
      bf16x8 a[2];
#pragma unroll
      for (int mi = 0; mi < 2; ++mi) {
        int row = m0 + mi * 16 + lr;
        if (row >= M) row = M - 1;
        const float* xp = &Xf[(size_t)row * H + kk * 32 + lg * 8];
        float4 u0 = *(const float4*)xp;
        float4 u1 = *(const float4*)(xp + 4);
        unsigned short t[8] = {f2bf(u0.x), f2bf(u0.y), f2bf(u0.z), f2bf(u0.w),
                               f2bf(u1.x), f2bf(u1.y), f2bf(u1.z), f2bf(u1.w)};
        a[mi] = *(const bf16x8*)t;
      }
#pragma unroll
      for (int nf = 0; nf < 8; ++nf) {
        bf16x8 bb = *(const bf16x8*)&Wp[(size_t)(kk * 8 + nf) * 512 + l * 8];
#pragma unroll
        for (int mi = 0; mi < 2; ++mi)
          acc[mi][nf] = __builtin_amdgcn_mfma_f32_16x16x32_bf16(a[mi], bb, acc[mi][nf], 0, 0, 0);
      }
    }
    float bv[8];
#pragma unroll
    for (int nf = 0; nf < 8; ++nf) bv[nf] = cvec[nf * 16 + lr];
#pragma unroll
    for (int mi = 0; mi < 2; ++mi)
#pragma unroll
      for (int r = 0; r < 4; ++r) {
        int row = m0 + mi * 16 + lg * 4 + r;
        if (row < M) {
#pragma unroll
          for (int nf = 0; nf < 8; ++nf)
            Y[(size_t)row * H + nf * 16 + lr] = f2bf(fmaxf(acc[mi][nf][r] + bv[nf], 0.f));
        }
      }
  } else {
    __shared__ int wtot[4];
    __shared__ int wbase[4];
    __shared__ int s_btot;
    __shared__ int s_carry;
    int N = M;
    int lane = tid & 63, wid = tid >> 6;
    if (tid == 0) s_carry = 0;
    __syncthreads();
    for (int base = 0; base < N; base += 1024) {
      int i0 = base + tid * 4;
      int v[4];
#pragma unroll
      for (int j = 0; j < 4; ++j) v[j] = (i0 + j < N) ? cnt[i0 + j] : 0;
      int s = v[0] + v[1] + v[2] + v[3];
      int incl = s;
#pragma unroll
      for (int o = 1; o < 64; o <<= 1) {
        int t = __shfl_up(incl, o, 64);
        if (lane >= o) incl += t;
      }
      if (lane == 63) wtot[wid] = incl;
      __syncthreads();
      if (tid == 0) {
        int run = 0;
        for (int w = 0; w < 4; ++w) { wbase[w] = run; run += wtot[w]; }
        s_btot = run;
      }
      __syncthreads();
      int e0 = s_carry + wbase[wid] + (incl - s);
#pragma unroll
      for (int j = 0; j < 4; ++j) {
        if (i0 + j < N) { off[i0 + j] = e0; pos[i0 + j] = e0; }
        e0 += v[j];
      }
      __syncthreads();
      if (tid == 0) s_carry += s_btot;
      __syncthreads();
    }
    if (tid == 0) off[N] = s_carry;
  }
}

// ---------------- fill: per-thread, one packed 16B CSR entry per edge ----------------
__global__ void fill_v2_kernel(const int* __restrict__ ei, const float* __restrict__ ew, int E,
                               int* __restrict__ pos, uint4* __restrict__ csr4) {
  int e = blockIdx.x * blockDim.x + threadIdx.x;
  if (e < E) {
    int d = ei[E + e];
    int p = atomicAdd(&pos[d], 1);
    csr4[p] = make_uint4((unsigned)ei[e], __float_as_uint(ew[e]), (unsigned)e, (unsigned)d);
  }
}

// ---------------- layer GEMM + LN + relu + residual (in-place x), MI=2 ----------------
__global__ __launch_bounds__(256) void gemm_layer_ln_kernel(
    const unsigned short* __restrict__ Agg, const unsigned short* __restrict__ WpRel,
    unsigned short* __restrict__ Xio, const unsigned short* __restrict__ WpRoot,
    const float* __restrict__ brel, const float* __restrict__ gamma,
    const float* __restrict__ beta, int M) {
  int l = threadIdx.x & 63, w = threadIdx.x >> 6;
  int lr = l & 15, lg = l >> 4;
  int m0 = blockIdx.x * 128 + w * 32;
  f32x4 acc[2][8] = {};
  for (int kk = 0; kk < 8; ++kk) {
    const unsigned short* X = (kk >= 4) ? Xio : Agg;
    const unsigned short* Wp = (kk >= 4) ? WpRoot : WpRel;
    int k4 = kk & 3;
    bf16x8 a[2] = {};
#pragma unroll
    for (int mi = 0; mi < 2; ++mi) {
      int row = m0 + mi * 16 + lr;
      if (row < M) a[mi] = *(const bf16x8*)&X[(size_t)row * H + k4 * 32 + lg * 8];
    }
#pragma unroll
    for (int nf = 0; nf < 8; ++nf) {
      bf16x8 b = *(const bf16x8*)&Wp[(size_t)(k4 * 8 + nf) * 512 + l * 8];
#pragma unroll
      for (int mi = 0; mi < 2; ++mi)
        acc[mi][nf] = __builtin_amdgcn_mfma_f32_16x16x32_bf16(a[mi], b, acc[mi][nf], 0, 0, 0);
    }
  }
  float bv[8], gv[8], bev[8];
#pragma unroll
  for (int nf = 0; nf < 8; ++nf) {
    int col = nf * 16 + lr;
    bv[nf] = brel[col]; gv[nf] = gamma[col]; bev[nf] = beta[col];
  }
#pragma unroll
  for (int mi = 0; mi < 2; ++mi) {
#pragma unroll
    for (int r = 0; r < 4; ++r) {
      int row = m0 + mi * 16 + lg * 4 + r;
      float hv[8], s1 = 0.f;
#pragma unroll
      for (int nf = 0; nf < 8; ++nf) { hv[nf] = acc[mi][nf][r] + bv[nf]; s1 += hv[nf]; }
      s1 += __shfl_xor(s1, 1, 64);
      s1 += __shfl_xor(s1, 2, 64);
      s1 += __shfl_xor(s1, 4, 64);
      s1 += __shfl_xor(s1, 8, 64);
      float mu = s1 * (1.0f / H);
      float s2 = 0.f;
#pragma unroll
      for (int nf = 0; nf < 8; ++nf) { float d = hv[nf] - mu; s2 += d * d; }
      s2 += __shfl_xor(s2, 1, 64);
      s2 += __shfl_xor(s2, 2, 64);
      s2 += __shfl_xor(s2, 4, 64);
      s2 += __shfl_xor(s2, 8, 64);
      float rstd = rsqrtf(s2 * (1.0f / H) + LN_EPS);
      if (row < M) {
#pragma unroll
        for (int nf = 0; nf < 8; ++nf) {
          int col = nf * 16 + lr;
          float v = fmaxf((hv[nf] - mu) * rstd * gv[nf] + bev[nf], 0.f);
          v += bf2f(Xio[(size_t)row * H + col]);
          Xio[(size_t)row * H + col] = f2bf(v);
        }
      }
    }
  }
}

// ---------------- decoder GEMMs fused: A = x@Wd1a + bd1 ; B = x@Wd1b, MI=2 ----------------
__global__ __launch_bounds__(256) void gemm_dec_kernel(
    const unsigned short* __restrict__ X, const unsigned short* __restrict__ WpA,
    const unsigned short* __restrict__ WpB, const float* __restrict__ bd1,
    unsigned short* __restrict__ Aout, unsigned short* __restrict__ Bout, int M) {
  int l = threadIdx.x & 63, w = threadIdx.x >> 6;
  int lr = l & 15, lg = l >> 4;
  int m0 = blockIdx.x * 128 + w * 32;
  f32x4 accA[2][8] = {};
  f32x4 accB[2][8] = {};
  for (int kk = 0; kk < 4; ++kk) {
    bf16x8 a[2];
#pragma unroll
    for (int mi = 0; mi < 2; ++mi) {
      int row = m0 + mi * 16 + lr;
      if (row >= M) row = M - 1;
      a[mi] = *(const bf16x8*)&X[(size_t)row * H + kk * 32 + lg * 8];
    }
#pragma unroll
    for (int nf = 0; nf < 8; ++nf) {
      bf16x8 bA = *(const bf16x8*)&WpA[(size_t)(kk * 8 + nf) * 512 + l * 8];
      bf16x8 bB = *(const bf16x8*)&WpB[(size_t)(kk * 8 + nf) * 512 + l * 8];
#pragma unroll
      for (int mi = 0; mi < 2; ++mi) {
        accA[mi][nf] = __builtin_amdgcn_mfma_f32_16x16x32_bf16(a[mi], bA, accA[mi][nf], 0, 0, 0);
        accB[mi][nf] = __builtin_amdgcn_mfma_f32_16x16x32_bf16(a[mi], bB, accB[mi][nf], 0, 0, 0);
      }
    }
  }
  float bdv[8];
#pragma unroll
  for (int nf = 0; nf < 8; ++nf) bdv[nf] = bd1[nf * 16 + lr];
#pragma unroll
  for (int mi = 0; mi < 2; ++mi)
#pragma unroll
    for (int r = 0; r < 4; ++r) {
      int row = m0 + mi * 16 + lg * 4 + r;
      if (row < M) {
#pragma unroll
        for (int nf = 0; nf < 8; ++nf) {
          int col = nf * 16 + lr;
          Aout[(size_t)row * H + col] = f2bf(accA[mi][nf][r] + bdv[nf]);
          Bout[(size_t)row * H + col] = f2bf(accB[mi][nf][r]);
        }
      }
    }
}

// ---------------- gather v4: 4 nodes/wave (16 lanes each, uint4 loads), 16-deep chunks ----------------
__global__ __launch_bounds__(256) void gather_agg_v4_kernel(
    const unsigned short* __restrict__ xbf, const int* __restrict__ off,
    const uint4* __restrict__ csr4, unsigned short* __restrict__ aggbf, int N) {
  int gw = (blockIdx.x * blockDim.x + threadIdx.x) >> 6;
  int lane = threadIdx.x & 63;
  int q = lane >> 4, li = lane & 15;
  int n = gw * 4 + q;
  if (n >= N) return;
  int s0 = off[n], s1 = off[n + 1];
  float a0 = 0.f, a1 = 0.f, a2 = 0.f, a3 = 0.f, a4 = 0.f, a5 = 0.f, a6 = 0.f, a7 = 0.f;
  for (int base = s0; base < s1; base += 16) {
    uint2 c[16];
#pragma unroll
    for (int j = 0; j < 16; ++j) {
      int id = base + j;
      c[j] = *(const uint2*)&csr4[id < s1 ? id : s1 - 1];
      if (id >= s1) c[j].y = 0;
    }
    uint4 v[16];
#pragma unroll
    for (int j = 0; j < 16; ++j)
      v[j] = *(const uint4*)&xbf[(size_t)c[j].x * H + li * 8];
#pragma unroll
    for (int j = 0; j < 16; ++j) {
      float w = __uint_as_float(c[j].y);
      a0 += w * bf2f((unsigned short)(v[j].x & 0xffffu));
      a1 += w * bf2f((unsigned short)(v[j].x >> 16));
      a2 += w * bf2f((unsigned short)(v[j].y & 0xffffu));
      a3 += w * bf2f((unsigned short)(v[j].y >> 16));
      a4 += w * bf2f((unsigned short)(v[j].z & 0xffffu));
      a5 += w * bf2f((unsigned short)(v[j].z >> 16));
      a6 += w * bf2f((unsigned short)(v[j].w & 0xffffu));
      a7 += w * bf2f((unsigned short)(v[j].w >> 16));
    }
  }
  unsigned short t[8] = {f2bf(a0), f2bf(a1), f2bf(a2), f2bf(a3),
                         f2bf(a4), f2bf(a5), f2bf(a6), f2bf(a7)};
  *(uint4*)&aggbf[(size_t)n * H + li * 8] = *(uint4*)t;
}

// ---------------- edge decoder v6: edge-parallel in CSR order (dst-locality for B) ----------------
__global__ __launch_bounds__(256) void edge_out_v6_kernel(
    const uint4* __restrict__ csr4, const float* __restrict__ af,
    const unsigned short* __restrict__ A, const unsigned short* __restrict__ B,
    const float* __restrict__ Wd1c, const float* __restrict__ Wd2,
    const float* __restrict__ bd2, float* __restrict__ out, int E) {
  int lane = threadIdx.x & 63;
  int sub = lane & 15;
  int grp = lane >> 4;
  float wc[8][8], w2[8];
#pragma unroll
  for (int i = 0; i < 8; ++i)
#pragma unroll
    for (int c = 0; c < 8; ++c) wc[i][c] = Wd1c[i * H + sub * 8 + c];
#pragma unroll
  for (int c = 0; c < 8; ++c) w2[c] = Wd2[sub * 8 + c];
  float b2 = bd2[0];
  int gw = (blockIdx.x * blockDim.x + threadIdx.x) >> 6;
  int nw = (gridDim.x * blockDim.x) >> 6;
  int n4 = (E + 3) >> 2;
  for (int e4 = gw; e4 < n4; e4 += nw) {
    int idx = e4 * 4 + grp;
    bool valid = idx < E;
    int ii = valid ? idx : E - 1;
    uint4 c = csr4[ii];
    uint4 va = *(const uint4*)&A[(size_t)c.x * H + sub * 8];
    uint4 vb = *(const uint4*)&B[(size_t)c.w * H + sub * 8];
    float4 f0 = *(const float4*)&af[(size_t)c.z * 8];
    float4 f1 = *(const float4*)&af[(size_t)c.z * 8 + 4];
    const unsigned* pa = (const unsigned*)&va;
    const unsigned* pb = (const unsigned*)&vb;
    float t[8];
#pragma unroll
    for (int q = 0; q < 4; ++q) {
      t[q * 2 + 0] = bf2f((unsigned short)(pa[q] & 0xffffu)) + bf2f((unsigned short)(pb[q] & 0xffffu));
      t[q * 2 + 1] = bf2f((unsigned short)(pa[q] >> 16)) + bf2f((unsigned short)(pb[q] >> 16));
    }
    float afv[8] = {f0.x, f0.y, f0.z, f0.w, f1.x, f1.y, f1.z, f1.w};
#pragma unroll
    for (int i = 0; i < 8; ++i)
#pragma unroll
      for (int cc = 0; cc < 8; ++cc) t[cc] += afv[i] * wc[i][cc];
    float p = 0.f;
#pragma unroll
    for (int cc = 0; cc < 8; ++cc) p += fmaxf(t[cc], 0.f) * w2[cc];
    p += __shfl_xor(p, 1, 64);
    p += __shfl_xor(p, 2, 64);
    p += __shfl_xor(p, 4, 64);
    p += __shfl_xor(p, 8, 64);
    if (valid && sub == 0) out[c.z] = p + b2;
  }
}

// ---------------- launch ----------------
extern "C" void kernel_launch(void* const* d_in, const int* in_sizes, int n_in, void* d_out,
                              int out_size, void* d_ws, size_t ws_size, hipStream_t stream) {
  const int* ei = (const int*)d_in[0];
  const float* af = (const float*)d_in[1];
  const float* h_old = (const float*)d_in[2];
  const float* Wf = (const float*)d_in[4];
  const float* bf = (const float*)d_in[5];
  const float* We1 = (const float*)d_in[6];
  const float* be1 = (const float*)d_in[7];
  const float* We2 = (const float*)d_in[8];
  const float* be2 = (const float*)d_in[9];
  const float* Wrel = (const float*)d_in[10];
  const float* brel = (const float*)d_in[11];
  const float* Wroot = (const float*)d_in[12];
  const float* gamma = (const float*)d_in[13];
  const float* beta = (const float*)d_in[14];
  const float* Wd1 = (const float*)d_in[15];
  const float* bd1 = (const float*)d_in[16];
  const float* Wd2 = (const float*)d_in[17];
  const float* bd2 = (const float*)d_in[18];
  const int N = in_sizes[2] / H;
  const int E = in_sizes[1] / 8;
  float* out = (float*)d_out;

  char* p = (char*)d_ws;
  auto alloc = [&](size_t b) { char* r = p; p += (b + 255) & ~(size_t)255; return r; };
  int* cnt = (int*)alloc((size_t)N * 4);
  int* pos = (int*)alloc((size_t)N * 4);
  int* off = (int*)alloc((size_t)(N + 1) * 4);
  uint4* csr4 = (uint4*)alloc((size_t)E * 16);
  float* ew = (float*)alloc((size_t)E * 4);
  float* cvec = (float*)alloc(H * 4);
  unsigned short* wpk = (unsigned short*)alloc((size_t)9 * 16384 * 2);
  unsigned short* xbf = (unsigned short*)alloc((size_t)N * H * 2);
  unsigned short* aggbf = (unsigned short*)alloc((size_t)N * H * 2);
  unsigned short* buf2 = (unsigned short*)alloc((size_t)N * H * 2);

  unsigned short* Abf = aggbf;  // reuse after layer loop
  unsigned short* Bbf = buf2;

  int cntBlocks = (E + 255) / 256;
  int gblocks = (N + 127) / 128;

  hipMemsetAsync(cnt, 0, (size_t)N * 4, stream);
  hipLaunchKernelGGL(pre1_kernel, dim3(EW_BLOCKS + cntBlocks + 1 + 72), dim3(256), 0, stream,
                     ei, af, We1, be1, We2, be2, ew, cnt, Wf, bf, cvec, Wrel, Wroot, Wd1, wpk,
                     E, cntBlocks);
  hipLaunchKernelGGL(pre2_kernel, dim3(gblocks + 1), dim3(256), 0, stream, h_old, wpk, cvec,
                     xbf, cnt, off, pos, N, gblocks);
  hipLaunchKernelGGL(fill_v2_kernel, dim3(cntBlocks), dim3(256), 0, stream, ei, ew, E, pos,
                     csr4);

  int gat4_blocks = (N + 15) / 16;
  for (int l = 0; l < 3; ++l) {
    hipLaunchKernelGGL(gather_agg_v4_kernel, dim3(gat4_blocks), dim3(256), 0, stream, xbf, off,
                       csr4, aggbf, N);
    hipLaunchKernelGGL(gemm_layer_ln_kernel, dim3(gblocks), dim3(256), 0, stream, aggbf,
                       wpk + (size_t)(1 + l) * 16384, xbf, wpk + (size_t)(4 + l) * 16384,
                       brel + l * H, gamma + l * H, beta + l * H, N);
  }

  hipLaunchKernelGGL(gemm_dec_kernel, dim3(gblocks), dim3(256), 0, stream, xbf,
                     wpk + (size_t)7 * 16384, wpk + (size_t)8 * 16384, bd1, Abf, Bbf, N);
  hipLaunchKernelGGL(edge_out_v6_kernel, dim3(4096), dim3(256), 0, stream, csr4, af, Abf, Bbf,
                     Wd1 + 2 * H * H, Wd2, bd2, out, E);
}